// Round 4
// baseline (597.981 us; speedup 1.0000x reference)
//
#include <hip/hip_runtime.h>

#define DD 128
#define BROWS 256

typedef __attribute__((ext_vector_type(8))) short bf16x8;
typedef __attribute__((ext_vector_type(4))) float f32x4;

__device__ __forceinline__ float b2f(unsigned short u) {
    return __uint_as_float(((unsigned)u) << 16);
}
__device__ __forceinline__ unsigned short f2b(float f) {
    unsigned u = __float_as_uint(f);
    unsigned r = (u + 0x7FFFu + ((u >> 16) & 1u)) >> 16;
    return (unsigned short)r;
}

// ---------------- CSR build ----------------

__global__ __launch_bounds__(256) void scan1_kernel(const int* __restrict__ cnt,
                                                    int* __restrict__ startv,
                                                    int* __restrict__ bsum, int n) {
    int i = blockIdx.x * 256 + threadIdx.x;
    int v = (i < n) ? cnt[i] : 0;
    int lane = threadIdx.x & 63, wid = threadIdx.x >> 6;
    int incl = v;
#pragma unroll
    for (int o = 1; o < 64; o <<= 1) {
        int t = __shfl_up(incl, o);
        if (lane >= o) incl += t;
    }
    __shared__ int wsum[4];
    __shared__ int wpre[4];
    if (lane == 63) wsum[wid] = incl;
    __syncthreads();
    if (threadIdx.x == 0) {
        int s = 0;
        for (int w2 = 0; w2 < 4; ++w2) { wpre[w2] = s; s += wsum[w2]; }
        bsum[blockIdx.x] = s;
    }
    __syncthreads();
    if (i < n) startv[i] = incl - v + wpre[wid];
}

__global__ __launch_bounds__(512) void scan2_kernel(int* bsum, int nb) {
    int i = threadIdx.x;
    int v = (i < nb) ? bsum[i] : 0;
    int lane = threadIdx.x & 63, wid = threadIdx.x >> 6;
    int incl = v;
#pragma unroll
    for (int o = 1; o < 64; o <<= 1) {
        int t = __shfl_up(incl, o);
        if (lane >= o) incl += t;
    }
    __shared__ int wsum[8];
    __shared__ int wpre[8];
    if (lane == 63) wsum[wid] = incl;
    __syncthreads();
    if (threadIdx.x == 0) {
        int s = 0;
        for (int w2 = 0; w2 < 8; ++w2) { wpre[w2] = s; s += wsum[w2]; }
    }
    __syncthreads();
    if (i < nb) bsum[i] = incl - v + wpre[wid];
}

__global__ __launch_bounds__(256) void scan3_kernel(int* startv, int* cursor,
                                                    const int* __restrict__ bsum,
                                                    int n, int E) {
    int i = blockIdx.x * 256 + threadIdx.x;
    if (i < n) {
        int s = startv[i] + bsum[i >> 8];
        startv[i] = s;
        cursor[i] = s;
    } else if (i == n) {
        startv[n] = E;
    }
}

__global__ __launch_bounds__(256) void fill_kernel(const int* __restrict__ ei,
                                                   const int* __restrict__ ety,
                                                   const float* __restrict__ ew,
                                                   int* cursor,
                                                   uint2* __restrict__ csre, int E) {
    int e = blockIdx.x * 256 + threadIdx.x;
    if (e >= E) return;
    int dst = ei[E + e];
    int p = atomicAdd(&cursor[dst], 1);
    uint2 rec;
    rec.x = ((unsigned)ei[e]) | (((unsigned)ety[e]) << 20);  // src | (rel<<20)
    rec.y = __float_as_uint(ew[e]);
    csre[p] = rec;
}

// ---------------- merged conversions + histogram ----------------
// block ranges: [0,bx) x0->xb ; [bx,bx+br) r0->r0b (swizzled) ;
//               [bx+br, +256) W transposes (swizzled, into wcat0/wcat1) ; rest: hist

__global__ __launch_bounds__(256) void prep_hist_kernel(
    const float* __restrict__ x0, unsigned short* __restrict__ xb, int bx, int n4x,
    const float* __restrict__ r0, unsigned short* __restrict__ r0b, int br, int n4r,
    const float* __restrict__ W0, const float* __restrict__ Ws0,
    const float* __restrict__ W1, const float* __restrict__ Ws1,
    unsigned short* __restrict__ wcat0, unsigned short* __restrict__ wcat1,
    const int* __restrict__ ei, int* __restrict__ cnt, int E) {
    int bid = blockIdx.x;
    if (bid < bx) {
        int i = bid * 256 + threadIdx.x;
        if (i < n4x) {
            float4 v = ((const float4*)x0)[i];
            ((ushort4*)xb)[i] = make_ushort4(f2b(v.x), f2b(v.y), f2b(v.z), f2b(v.w));
        }
        return;
    }
    bid -= bx;
    if (bid < br) {
        int i = bid * 256 + threadIdx.x;
        if (i < n4r) {
            float4 v = ((const float4*)r0)[i];
            int c0 = (i * 4) & 127;
            int row = (i * 4) >> 7;
            int slot = c0 >> 3;
            int dst = row * DD + (((slot ^ (row & 15)) << 3) | (c0 & 7));
            *(ushort4*)(r0b + dst) = make_ushort4(f2b(v.x), f2b(v.y), f2b(v.z), f2b(v.w));
        }
        return;
    }
    bid -= br;
    if (bid < 256) {
        int which = bid >> 6;
        int i = (bid & 63) * 256 + threadIdx.x;  // 0..16383
        int cc = i >> 7, k = i & 127;
        const float* Wsel = which == 0 ? W0 : which == 1 ? Ws0 : which == 2 ? W1 : Ws1;
        unsigned short* base = (which < 2) ? wcat0 : wcat1;
        unsigned short* Osel = base + ((which & 1) ? DD * DD : 0);
        int dst = cc * DD + ((((k >> 3) ^ (cc & 15)) << 3) | (k & 7));
        Osel[dst] = f2b(Wsel[k * DD + cc]);   // swizzled Wt[c][k]
        return;
    }
    bid -= 256;
    int e = bid * 256 + threadIdx.x;
    if (e < E) atomicAdd(&cnt[ei[E + e]], 1);
}

// ---------------- fused layer: aggregate (rel from LDS) + dual GEMM ----------------
// node blocks [0,nblk): 256 rows each. block nblk: rel-path f32 GEMM.
// LDS: sA holds rel table during agg, then bf16 agg tile; sB holds [W | Wself] swizzled.

__global__ __launch_bounds__(512) void fused_layer_kernel(
    const unsigned short* __restrict__ gx,      // bf16 [N,128]: gather + self input
    const unsigned short* __restrict__ rel_sw,  // bf16 swizzled [R*128]
    const unsigned short* __restrict__ wcat,    // bf16 swizzled [2*128*128] = [W | Wself]
    const int* __restrict__ startv, const uint2* __restrict__ csre,
    float* __restrict__ outf, unsigned short* __restrict__ outb,
    const float* __restrict__ relA, const float* __restrict__ relW,
    float* __restrict__ reloutf, unsigned short* __restrict__ reloutb,
    int N, int R, int relu, int nblk)
{
    __shared__ unsigned short sA[BROWS * DD];   // 64 KB
    __shared__ unsigned short sB[2 * DD * DD];  // 64 KB
    int tid = threadIdx.x;

    if (blockIdx.x == nblk) {
        // ---- rel-path f32 GEMM (200 rows) ----
        float* sWf = (float*)sB;
        for (int i = tid; i < DD * DD / 4; i += 512)
            ((float4*)sWf)[i] = ((const float4*)relW)[i];
        __syncthreads();
        int j4 = (tid & 31) << 2;
        int rslot = tid >> 5;                    // 0..15
        for (int row = rslot; row < R; row += 16) {
            const float4* A4 = (const float4*)(relA + (size_t)row * DD);
            float4 acc = make_float4(0.f, 0.f, 0.f, 0.f);
#pragma unroll
            for (int k4 = 0; k4 < 32; ++k4) {
                float4 av = A4[k4];
                const float* wp = sWf + (k4 * 4) * DD + j4;
                float4 w0 = *(const float4*)(wp);
                float4 w1 = *(const float4*)(wp + DD);
                float4 w2 = *(const float4*)(wp + 2 * DD);
                float4 w3 = *(const float4*)(wp + 3 * DD);
                acc.x += av.x * w0.x + av.y * w1.x + av.z * w2.x + av.w * w3.x;
                acc.y += av.x * w0.y + av.y * w1.y + av.z * w2.y + av.w * w3.y;
                acc.z += av.x * w0.z + av.y * w1.z + av.z * w2.z + av.w * w3.z;
                acc.w += av.x * w0.w + av.y * w1.w + av.z * w2.w + av.w * w3.w;
            }
            if (relu) {
                acc.x = fmaxf(acc.x, 0.f); acc.y = fmaxf(acc.y, 0.f);
                acc.z = fmaxf(acc.z, 0.f); acc.w = fmaxf(acc.w, 0.f);
            }
            if (reloutf) *(float4*)(reloutf + (size_t)row * DD + j4) = acc;
            if (reloutb) {
                int slot = j4 >> 3;
                int dst = row * DD + (((slot ^ (row & 15)) << 3) | (j4 & 7));
                *(ushort4*)(reloutb + dst) =
                    make_ushort4(f2b(acc.x), f2b(acc.y), f2b(acc.z), f2b(acc.w));
            }
        }
        return;
    }

    int brow = blockIdx.x * BROWS;

    // ---- stage rel table into sA, weights into sB ----
    {
        int nrel8 = R * DD / 8;
        const bf16x8* rs = (const bf16x8*)rel_sw;
        bf16x8* da = (bf16x8*)sA;
        for (int i = tid; i < nrel8; i += 512) da[i] = rs[i];
        const uint4* wsrc = (const uint4*)wcat;
        uint4* db = (uint4*)sB;
        for (int i = tid; i < 2 * DD * DD / 8; i += 512) db[i] = wsrc[i];
    }
    __syncthreads();

    // ---- aggregation: 2 lanes/node, 64 elems/lane, rel from LDS ----
    int node = tid >> 1, half = tid & 1;
    int gnode = brow + node;
    int s = 0, epos = 0;
    if (gnode < N) { s = startv[gnode]; epos = startv[gnode + 1]; }
    float a[64];
#pragma unroll
    for (int j = 0; j < 64; ++j) a[j] = 0.f;
    const bf16x8* X8 = (const bf16x8*)gx;
    const bf16x8* R8 = (const bf16x8*)sA;
    for (int i = s; i < epos; ++i) {
        uint2 p = csre[i];
        int src = (int)(p.x & 0xFFFFFu);
        int t = (int)(p.x >> 20);
        float w = __uint_as_float(p.y);
        bf16x8 xv[8], rv[8];
#pragma unroll
        for (int j = 0; j < 8; ++j) xv[j] = X8[(size_t)src * 16 + half * 8 + j];
#pragma unroll
        for (int j = 0; j < 8; ++j) rv[j] = R8[t * 16 + ((half * 8 + j) ^ (t & 15))];
#pragma unroll
        for (int j = 0; j < 8; ++j)
#pragma unroll
            for (int q = 0; q < 8; ++q)
                a[j * 8 + q] += (b2f((unsigned short)xv[j][q]) -
                                 b2f((unsigned short)rv[j][q])) * w;
    }
    __syncthreads();   // all lanes done reading rel table from sA

    // ---- dump bf16 agg tile into sA (XOR-swizzled slots) ----
    {
        bf16x8* da = (bf16x8*)sA;
#pragma unroll
        for (int j = 0; j < 8; ++j) {
            int slot = half * 8 + j;
            bf16x8 ov;
#pragma unroll
            for (int q = 0; q < 8; ++q) ov[q] = (short)f2b(a[j * 8 + q]);
            da[node * 16 + (slot ^ (node & 15))] = ov;
        }
    }
    __syncthreads();

    // ---- dual GEMM: out = agg@W + gx@Wself (swapped-operand MFMA) ----
    int w = tid >> 6, l = tid & 63;
    int lr = l & 15, lk = l >> 4;
    int trow = w * 32;
    f32x4 acc[2][8];
#pragma unroll
    for (int rt = 0; rt < 2; ++rt)
#pragma unroll
        for (int ct = 0; ct < 8; ++ct) acc[rt][ct] = (f32x4){0.f, 0.f, 0.f, 0.f};

    const bf16x8* sA8 = (const bf16x8*)sA;
    const bf16x8* sW8 = (const bf16x8*)sB;
#pragma unroll
    for (int kb = 0; kb < 4; ++kb) {
        int slot = kb * 4 + lk;
        int so = slot ^ lr;
        bf16x8 a0 = sA8[(trow + lr) * 16 + so];
        bf16x8 a1 = sA8[(trow + 16 + lr) * 16 + so];
        int koff = kb * 32 + lk * 8;
        int r0 = brow + trow + lr, r1 = r0 + 16;
        bf16x8 x0 = {}, x1 = {};
        if (r0 < N) x0 = *(const bf16x8*)(gx + (size_t)r0 * DD + koff);
        if (r1 < N) x1 = *(const bf16x8*)(gx + (size_t)r1 * DD + koff);
#pragma unroll
        for (int ct = 0; ct < 8; ++ct) {
            bf16x8 bw = sW8[(ct * 16 + lr) * 16 + so];
            bf16x8 bs = sW8[2048 + (ct * 16 + lr) * 16 + so];
            acc[0][ct] = __builtin_amdgcn_mfma_f32_16x16x32_bf16(bw, a0, acc[0][ct], 0, 0, 0);
            acc[0][ct] = __builtin_amdgcn_mfma_f32_16x16x32_bf16(bs, x0, acc[0][ct], 0, 0, 0);
            acc[1][ct] = __builtin_amdgcn_mfma_f32_16x16x32_bf16(bw, a1, acc[1][ct], 0, 0, 0);
            acc[1][ct] = __builtin_amdgcn_mfma_f32_16x16x32_bf16(bs, x1, acc[1][ct], 0, 0, 0);
        }
    }

    // epilogue: C^T layout -> lane holds C[row][ct*16 + lk*4 .. +3], vectorized stores
#pragma unroll
    for (int rt = 0; rt < 2; ++rt) {
        int row = brow + trow + rt * 16 + lr;
        if (row < N) {
#pragma unroll
            for (int ct = 0; ct < 8; ++ct) {
                f32x4 v = acc[rt][ct];
                if (relu) {
                    v[0] = fmaxf(v[0], 0.f); v[1] = fmaxf(v[1], 0.f);
                    v[2] = fmaxf(v[2], 0.f); v[3] = fmaxf(v[3], 0.f);
                }
                int cb = ct * 16 + lk * 4;
                if (outf) *(f32x4*)(outf + (size_t)row * DD + cb) = v;
                if (outb) {
                    *(ushort4*)(outb + (size_t)row * DD + cb) =
                        make_ushort4(f2b(v[0]), f2b(v[1]), f2b(v[2]), f2b(v[3]));
                }
            }
        }
    }
}

// ---------------- launcher ----------------

extern "C" void kernel_launch(void* const* d_in, const int* in_sizes, int n_in,
                              void* d_out, int out_size, void* d_ws, size_t ws_size,
                              hipStream_t stream) {
    const int*   ei  = (const int*)d_in[0];
    const int*   ety = (const int*)d_in[1];
    const float* ew  = (const float*)d_in[2];
    const float* x0  = (const float*)d_in[3];
    const float* r0  = (const float*)d_in[4];
    const float* W0  = (const float*)d_in[5];
    const float* Ws0 = (const float*)d_in[6];
    const float* Wr0 = (const float*)d_in[7];
    const float* W1  = (const float*)d_in[8];
    const float* Ws1 = (const float*)d_in[9];
    const float* Wr1 = (const float*)d_in[10];

    const int E = in_sizes[1];
    const int N = in_sizes[3] / DD;
    const int R = in_sizes[4] / DD;

    float* out_x = (float*)d_out;                 // [N,128] f32
    float* out_r = out_x + (size_t)N * DD;        // [R,128] f32

    char* w = (char*)d_ws;
    size_t off = 0;
    auto alloc = [&](size_t bytes) {
        void* p = w + off;
        off += (bytes + 255) & ~(size_t)255;
        return p;
    };
    unsigned short* xb    = (unsigned short*)alloc((size_t)N * DD * 2);  // 25.6 MB
    unsigned short* x1b   = (unsigned short*)alloc((size_t)N * DD * 2);  // 25.6 MB
    unsigned short* r0b   = (unsigned short*)alloc((size_t)R * DD * 2);  // swizzled
    unsigned short* rel1b = (unsigned short*)alloc((size_t)R * DD * 2);  // swizzled
    unsigned short* wcat0 = (unsigned short*)alloc((size_t)2 * DD * DD * 2);
    unsigned short* wcat1 = (unsigned short*)alloc((size_t)2 * DD * DD * 2);
    float* rel1   = (float*)alloc((size_t)R * DD * 4);
    int*   startv = (int*)alloc((size_t)(N + 1) * 4);
    int*   cursor = (int*)alloc((size_t)N * 4);
    int*   bsum   = (int*)alloc(512 * 4);
    uint2* csre   = (uint2*)alloc((size_t)E * 8);
    (void)ws_size; (void)n_in; (void)out_size;

    // --- CSR build + conversions ---
    int* cnt = cursor;
    hipMemsetAsync(cnt, 0, (size_t)N * 4, stream);
    int ebl = (E + 255) / 256;
    int nb  = (N + 255) / 256;
    int n4x = N * 32, n4r = R * 32;
    int bx = (n4x + 255) / 256, br = (n4r + 255) / 256;
    prep_hist_kernel<<<bx + br + 256 + ebl, 256, 0, stream>>>(
        x0, xb, bx, n4x, r0, r0b, br, n4r,
        W0, Ws0, W1, Ws1, wcat0, wcat1, ei, cnt, E);
    scan1_kernel<<<nb, 256, 0, stream>>>(cnt, startv, bsum, N);
    scan2_kernel<<<1, 512, 0, stream>>>(bsum, nb);
    scan3_kernel<<<(N + 1 + 255) / 256, 256, 0, stream>>>(startv, cursor, bsum, N, E);
    fill_kernel<<<ebl, 256, 0, stream>>>(ei, ety, ew, cursor, csre, E);

    int nblk = (N + BROWS - 1) / BROWS;

    // --- layer 0: x1b = relu(agg@W0 + x0@Wself0); rel1 = relu(r0@Wrel0) ---
    fused_layer_kernel<<<nblk + 1, 512, 0, stream>>>(
        xb, r0b, wcat0, startv, csre,
        nullptr, x1b, r0, Wr0, rel1, rel1b, N, R, 1, nblk);

    // --- layer 1: out_x = agg@W1 + x1@Wself1; out_r = rel1@Wrel1 ---
    fused_layer_kernel<<<nblk + 1, 512, 0, stream>>>(
        x1b, rel1b, wcat1, startv, csre,
        out_x, nullptr, rel1, Wr1, out_r, nullptr, N, R, 0, nblk);
}

// Round 5
// 314.263 us; speedup vs baseline: 1.9028x; 1.9028x over previous
//
#include <hip/hip_runtime.h>

#define DD 128

typedef __attribute__((ext_vector_type(8))) short bf16x8;
typedef __attribute__((ext_vector_type(4))) float f32x4;

__device__ __forceinline__ float b2f(unsigned short u) {
    return __uint_as_float(((unsigned)u) << 16);
}
__device__ __forceinline__ unsigned short f2b(float f) {
    unsigned u = __float_as_uint(f);
    unsigned r = (u + 0x7FFFu + ((u >> 16) & 1u)) >> 16;
    return (unsigned short)r;
}

// ---------------- CSR build ----------------

__global__ __launch_bounds__(256) void scan1_kernel(const int* __restrict__ cnt,
                                                    int* __restrict__ startv,
                                                    int* __restrict__ bsum, int n) {
    int i = blockIdx.x * 256 + threadIdx.x;
    int v = (i < n) ? cnt[i] : 0;
    int lane = threadIdx.x & 63, wid = threadIdx.x >> 6;
    int incl = v;
#pragma unroll
    for (int o = 1; o < 64; o <<= 1) {
        int t = __shfl_up(incl, o);
        if (lane >= o) incl += t;
    }
    __shared__ int wsum[4];
    __shared__ int wpre[4];
    if (lane == 63) wsum[wid] = incl;
    __syncthreads();
    if (threadIdx.x == 0) {
        int s = 0;
        for (int w2 = 0; w2 < 4; ++w2) { wpre[w2] = s; s += wsum[w2]; }
        bsum[blockIdx.x] = s;
    }
    __syncthreads();
    if (i < n) startv[i] = incl - v + wpre[wid];
}

__global__ __launch_bounds__(512) void scan2_kernel(int* bsum, int nb) {
    int i = threadIdx.x;
    int v = (i < nb) ? bsum[i] : 0;
    int lane = threadIdx.x & 63, wid = threadIdx.x >> 6;
    int incl = v;
#pragma unroll
    for (int o = 1; o < 64; o <<= 1) {
        int t = __shfl_up(incl, o);
        if (lane >= o) incl += t;
    }
    __shared__ int wsum[8];
    __shared__ int wpre[8];
    if (lane == 63) wsum[wid] = incl;
    __syncthreads();
    if (threadIdx.x == 0) {
        int s = 0;
        for (int w2 = 0; w2 < 8; ++w2) { wpre[w2] = s; s += wsum[w2]; }
    }
    __syncthreads();
    if (i < nb) bsum[i] = incl - v + wpre[wid];
}

__global__ __launch_bounds__(256) void scan3_kernel(int* startv, int* cursor,
                                                    const int* __restrict__ bsum,
                                                    int n, int E) {
    int i = blockIdx.x * 256 + threadIdx.x;
    if (i < n) {
        int s = startv[i] + bsum[i >> 8];
        startv[i] = s;
        cursor[i] = s;
    } else if (i == n) {
        startv[n] = E;
    }
}

__global__ __launch_bounds__(256) void fill_kernel(const int* __restrict__ ei,
                                                   const int* __restrict__ ety,
                                                   const float* __restrict__ ew,
                                                   int* cursor,
                                                   uint2* __restrict__ csre, int E) {
    int e = blockIdx.x * 256 + threadIdx.x;
    if (e >= E) return;
    int dst = ei[E + e];
    int p = atomicAdd(&cursor[dst], 1);
    uint2 rec;
    rec.x = ((unsigned)ei[e]) | (((unsigned)ety[e]) << 20);  // src | (rel<<20)
    rec.y = __float_as_uint(ew[e]);
    csre[p] = rec;
}

// ---------------- merged conversions + histogram ----------------
// blocks: [0,bx) x0->xb ; [bx,bx+br) r0->r0b ; [.., +256) W transposes ; rest: hist

__global__ __launch_bounds__(256) void prep_hist_kernel(
    const float* __restrict__ x0, unsigned short* __restrict__ xb, int bx, int n4x,
    const float* __restrict__ r0, unsigned short* __restrict__ r0b, int br, int n4r,
    const float* __restrict__ W0, const float* __restrict__ Ws0,
    const float* __restrict__ W1, const float* __restrict__ Ws1,
    unsigned short* __restrict__ wt0a, unsigned short* __restrict__ wt0s,
    unsigned short* __restrict__ wt1a, unsigned short* __restrict__ wt1s,
    const int* __restrict__ ei, int* __restrict__ cnt, int E) {
    int bid = blockIdx.x;
    if (bid < bx) {
        int i = bid * 256 + threadIdx.x;
        if (i < n4x) {
            float4 v = ((const float4*)x0)[i];
            ((ushort4*)xb)[i] = make_ushort4(f2b(v.x), f2b(v.y), f2b(v.z), f2b(v.w));
        }
        return;
    }
    bid -= bx;
    if (bid < br) {
        int i = bid * 256 + threadIdx.x;
        if (i < n4r) {
            float4 v = ((const float4*)r0)[i];
            ((ushort4*)r0b)[i] = make_ushort4(f2b(v.x), f2b(v.y), f2b(v.z), f2b(v.w));
        }
        return;
    }
    bid -= br;
    if (bid < 256) {
        int which = bid >> 6;
        int i = (bid & 63) * 256 + threadIdx.x;  // 0..16383
        int cc = i >> 7, k = i & 127;
        const float* Wsel = which == 0 ? W0 : which == 1 ? Ws0 : which == 2 ? W1 : Ws1;
        unsigned short* Osel = which == 0 ? wt0a : which == 1 ? wt0s : which == 2 ? wt1a : wt1s;
        Osel[i] = f2b(Wsel[k * DD + cc]);      // Wt[c][k] = W[k][c]
        return;
    }
    bid -= 256;
    int e = bid * 256 + threadIdx.x;
    if (e < E) atomicAdd(&cnt[ei[E + e]], 1);
}

// ---------------- aggregation: aggb[n] = bf16( sum_e w*(x[src]-rel[t]) ) ----------------
// 16 lanes/slot, each slot owns 2 nodes (n, n+16); 2-edge unroll per node
// -> 4 independent gather chains per lane, 16 per wave. Inactive edges clamp
// to csre[0] with weight 0 (branch-free).

__global__ __launch_bounds__(256) void aggregate_kernel(
    const unsigned short* __restrict__ xb, const unsigned short* __restrict__ relb,
    const int* __restrict__ startv, const uint2* __restrict__ csre,
    unsigned short* __restrict__ aggb, int n) {
    int slot = threadIdx.x >> 4;      // 0..15
    int c = threadIdx.x & 15;         // 16B chunk within the 256B bf16 row
    int n0 = blockIdx.x * 32 + slot;
    int n1 = n0 + 16;
    int i0 = 0, e0 = 0, i1 = 0, e1 = 0;
    if (n0 < n) { i0 = startv[n0]; e0 = startv[n0 + 1]; }
    if (n1 < n) { i1 = startv[n1]; e1 = startv[n1 + 1]; }
    const bf16x8* X = (const bf16x8*)xb;
    const bf16x8* Rl = (const bf16x8*)relb;
    float p0[8], q0[8], p1[8], q1[8];
#pragma unroll
    for (int j = 0; j < 8; ++j) { p0[j] = 0.f; q0[j] = 0.f; p1[j] = 0.f; q1[j] = 0.f; }
    while (i0 < e0 || i1 < e1) {
        bool v00 = i0 < e0, v01 = i0 + 1 < e0;
        bool v10 = i1 < e1, v11 = i1 + 1 < e1;
        uint2 c00 = csre[v00 ? i0 : 0];
        uint2 c01 = csre[v01 ? i0 + 1 : 0];
        uint2 c10 = csre[v10 ? i1 : 0];
        uint2 c11 = csre[v11 ? i1 + 1 : 0];
        float w00 = v00 ? __uint_as_float(c00.y) : 0.f;
        float w01 = v01 ? __uint_as_float(c01.y) : 0.f;
        float w10 = v10 ? __uint_as_float(c10.y) : 0.f;
        float w11 = v11 ? __uint_as_float(c11.y) : 0.f;
        bf16x8 x00 = X[(size_t)(c00.x & 0xFFFFFu) * 16 + c];
        bf16x8 x01 = X[(size_t)(c01.x & 0xFFFFFu) * 16 + c];
        bf16x8 x10 = X[(size_t)(c10.x & 0xFFFFFu) * 16 + c];
        bf16x8 x11 = X[(size_t)(c11.x & 0xFFFFFu) * 16 + c];
        bf16x8 r00 = Rl[(c00.x >> 20) * 16 + c];
        bf16x8 r01 = Rl[(c01.x >> 20) * 16 + c];
        bf16x8 r10 = Rl[(c10.x >> 20) * 16 + c];
        bf16x8 r11 = Rl[(c11.x >> 20) * 16 + c];
#pragma unroll
        for (int j = 0; j < 8; ++j) {
            p0[j] += (b2f((unsigned short)x00[j]) - b2f((unsigned short)r00[j])) * w00;
            q0[j] += (b2f((unsigned short)x01[j]) - b2f((unsigned short)r01[j])) * w01;
            p1[j] += (b2f((unsigned short)x10[j]) - b2f((unsigned short)r10[j])) * w10;
            q1[j] += (b2f((unsigned short)x11[j]) - b2f((unsigned short)r11[j])) * w11;
        }
        i0 = min(i0 + 2, e0);
        i1 = min(i1 + 2, e1);
    }
    if (n0 < n) {
        bf16x8 ov;
#pragma unroll
        for (int j = 0; j < 8; ++j) ov[j] = (short)f2b(p0[j] + q0[j]);
        ((bf16x8*)aggb)[(size_t)n0 * 16 + c] = ov;
    }
    if (n1 < n) {
        bf16x8 ov;
#pragma unroll
        for (int j = 0; j < 8; ++j) ov[j] = (short)f2b(p1[j] + q1[j]);
        ((bf16x8*)aggb)[(size_t)n1 * 16 + c] = ov;
    }
}

// ---------------- fused dual GEMM via MFMA + rel-path f32 GEMM side blocks ----------
// blocks [0,gbl): out = A@W + X@Wself (swapped-operand MFMA, C^T vectorized stores).
// blocks [gbl, gbl+2): rel path f32 GEMM (200 rows, rows strided by 16).

__global__ __launch_bounds__(256) void mfma_dual_gemm_kernel(
    const unsigned short* __restrict__ A, const unsigned short* __restrict__ X,
    const unsigned short* __restrict__ WtA, const unsigned short* __restrict__ WtX,
    float* __restrict__ outf, unsigned short* __restrict__ outb,
    int nrows, int relu,
    const float* __restrict__ relA, const float* __restrict__ relW,
    float* __restrict__ reloutf, unsigned short* __restrict__ reloutb,
    int R, int gbl) {
    __shared__ unsigned short sW[2][DD * DD];   // 64 KB (rel branch reuses as f32)

    if ((int)blockIdx.x >= gbl) {
        // ---- rel-path f32 GEMM ----
        float* sWf = (float*)&sW[0][0];
        for (int i = threadIdx.x; i < DD * DD / 4; i += 256)
            ((float4*)sWf)[i] = ((const float4*)relW)[i];
        __syncthreads();
        int rb = blockIdx.x - gbl;               // 0..1
        int j4 = (threadIdx.x & 31) << 2;
        int rslot = (threadIdx.x >> 5) + rb * 8; // 0..15
        for (int row = rslot; row < R; row += 16) {
            const float4* A4 = (const float4*)(relA + (size_t)row * DD);
            float4 acc = make_float4(0.f, 0.f, 0.f, 0.f);
#pragma unroll
            for (int k4 = 0; k4 < 32; ++k4) {
                float4 av = A4[k4];
                const float* wp = sWf + (k4 * 4) * DD + j4;
                float4 w0 = *(const float4*)(wp);
                float4 w1 = *(const float4*)(wp + DD);
                float4 w2 = *(const float4*)(wp + 2 * DD);
                float4 w3 = *(const float4*)(wp + 3 * DD);
                acc.x += av.x * w0.x + av.y * w1.x + av.z * w2.x + av.w * w3.x;
                acc.y += av.x * w0.y + av.y * w1.y + av.z * w2.y + av.w * w3.y;
                acc.z += av.x * w0.z + av.y * w1.z + av.z * w2.z + av.w * w3.z;
                acc.w += av.x * w0.w + av.y * w1.w + av.z * w2.w + av.w * w3.w;
            }
            if (relu) {
                acc.x = fmaxf(acc.x, 0.f); acc.y = fmaxf(acc.y, 0.f);
                acc.z = fmaxf(acc.z, 0.f); acc.w = fmaxf(acc.w, 0.f);
            }
            if (reloutf) *(float4*)(reloutf + (size_t)row * DD + j4) = acc;
            if (reloutb) {
                *(ushort4*)(reloutb + (size_t)row * DD + j4) =
                    make_ushort4(f2b(acc.x), f2b(acc.y), f2b(acc.z), f2b(acc.w));
            }
        }
        return;
    }

    for (int i = threadIdx.x; i < 2048; i += 256) {
        int row = i >> 4, slot = i & 15;
        int so = (slot ^ (row & 15)) * 8;
        *(float4*)&sW[0][row * DD + so] = ((const float4*)WtA)[i];
        *(float4*)&sW[1][row * DD + so] = ((const float4*)WtX)[i];
    }
    __syncthreads();
    int w = threadIdx.x >> 6, l = threadIdx.x & 63;
    int lr = l & 15, lk = l >> 4;
    int brow = blockIdx.x * 128 + w * 32;
    int r0 = brow + lr, r1 = brow + 16 + lr;
    bool v0 = r0 < nrows, v1 = r1 < nrows;

    f32x4 acc[2][8];
#pragma unroll
    for (int rt = 0; rt < 2; ++rt)
#pragma unroll
        for (int ct = 0; ct < 8; ++ct) acc[rt][ct] = (f32x4){0.f, 0.f, 0.f, 0.f};

#pragma unroll
    for (int kb = 0; kb < 4; ++kb) {
        int koff = kb * 32 + lk * 8;
        bf16x8 a0 = {}, a1 = {}, x0 = {}, x1 = {};
        if (v0) {
            a0 = *(const bf16x8*)(A + (size_t)r0 * DD + koff);
            x0 = *(const bf16x8*)(X + (size_t)r0 * DD + koff);
        }
        if (v1) {
            a1 = *(const bf16x8*)(A + (size_t)r1 * DD + koff);
            x1 = *(const bf16x8*)(X + (size_t)r1 * DD + koff);
        }
#pragma unroll
        for (int ct = 0; ct < 8; ++ct) {
            int wrow = ct * 16 + lr;
            int slot = kb * 4 + lk;
            int so = (slot ^ (wrow & 15)) * 8;
            bf16x8 bw = *(const bf16x8*)&sW[0][wrow * DD + so];
            bf16x8 bs = *(const bf16x8*)&sW[1][wrow * DD + so];
            acc[0][ct] = __builtin_amdgcn_mfma_f32_16x16x32_bf16(bw, a0, acc[0][ct], 0, 0, 0);
            acc[0][ct] = __builtin_amdgcn_mfma_f32_16x16x32_bf16(bs, x0, acc[0][ct], 0, 0, 0);
            acc[1][ct] = __builtin_amdgcn_mfma_f32_16x16x32_bf16(bw, a1, acc[1][ct], 0, 0, 0);
            acc[1][ct] = __builtin_amdgcn_mfma_f32_16x16x32_bf16(bs, x1, acc[1][ct], 0, 0, 0);
        }
    }

#pragma unroll
    for (int rt = 0; rt < 2; ++rt) {
        int row = brow + rt * 16 + lr;
        if (row < nrows) {
#pragma unroll
            for (int ct = 0; ct < 8; ++ct) {
                f32x4 v = acc[rt][ct];
                if (relu) {
                    v[0] = fmaxf(v[0], 0.f); v[1] = fmaxf(v[1], 0.f);
                    v[2] = fmaxf(v[2], 0.f); v[3] = fmaxf(v[3], 0.f);
                }
                int cb = ct * 16 + lk * 4;
                if (outf) *(f32x4*)(outf + (size_t)row * DD + cb) = v;
                if (outb) {
                    *(ushort4*)(outb + (size_t)row * DD + cb) =
                        make_ushort4(f2b(v[0]), f2b(v[1]), f2b(v[2]), f2b(v[3]));
                }
            }
        }
    }
}

// ---------------- launcher ----------------

extern "C" void kernel_launch(void* const* d_in, const int* in_sizes, int n_in,
                              void* d_out, int out_size, void* d_ws, size_t ws_size,
                              hipStream_t stream) {
    const int*   ei  = (const int*)d_in[0];
    const int*   ety = (const int*)d_in[1];
    const float* ew  = (const float*)d_in[2];
    const float* x0  = (const float*)d_in[3];
    const float* r0  = (const float*)d_in[4];
    const float* W0  = (const float*)d_in[5];
    const float* Ws0 = (const float*)d_in[6];
    const float* Wr0 = (const float*)d_in[7];
    const float* W1  = (const float*)d_in[8];
    const float* Ws1 = (const float*)d_in[9];
    const float* Wr1 = (const float*)d_in[10];

    const int E = in_sizes[1];
    const int N = in_sizes[3] / DD;
    const int R = in_sizes[4] / DD;

    float* out_x = (float*)d_out;                 // [N,128] f32
    float* out_r = out_x + (size_t)N * DD;        // [R,128] f32

    char* w = (char*)d_ws;
    size_t off = 0;
    auto alloc = [&](size_t bytes) {
        void* p = w + off;
        off += (bytes + 255) & ~(size_t)255;
        return p;
    };
    unsigned short* aggb  = (unsigned short*)alloc((size_t)N * DD * 2);  // 25.6 MB
    unsigned short* xb    = (unsigned short*)alloc((size_t)N * DD * 2);  // 25.6 MB
    unsigned short* r0b   = (unsigned short*)alloc((size_t)R * DD * 2);
    unsigned short* rel1b = (unsigned short*)alloc((size_t)R * DD * 2);
    unsigned short* wt0a  = (unsigned short*)alloc((size_t)DD * DD * 2);
    unsigned short* wt0s  = (unsigned short*)alloc((size_t)DD * DD * 2);
    unsigned short* wt1a  = (unsigned short*)alloc((size_t)DD * DD * 2);
    unsigned short* wt1s  = (unsigned short*)alloc((size_t)DD * DD * 2);
    float* rel1   = (float*)alloc((size_t)R * DD * 4);
    int*   startv = (int*)alloc((size_t)(N + 1) * 4);
    int*   cursor = (int*)alloc((size_t)N * 4);
    int*   bsum   = (int*)alloc(512 * 4);
    uint2* csre   = (uint2*)alloc((size_t)E * 8);
    (void)ws_size; (void)n_in; (void)out_size;

    // --- CSR build + conversions ---
    int* cnt = cursor;
    hipMemsetAsync(cnt, 0, (size_t)N * 4, stream);
    int ebl = (E + 255) / 256;
    int nb  = (N + 255) / 256;
    int n4x = N * 32, n4r = R * 32;
    int bx = (n4x + 255) / 256, br = (n4r + 255) / 256;
    prep_hist_kernel<<<bx + br + 256 + ebl, 256, 0, stream>>>(
        x0, xb, bx, n4x, r0, r0b, br, n4r,
        W0, Ws0, W1, Ws1, wt0a, wt0s, wt1a, wt1s, ei, cnt, E);
    scan1_kernel<<<nb, 256, 0, stream>>>(cnt, startv, bsum, N);
    scan2_kernel<<<1, 512, 0, stream>>>(bsum, nb);
    scan3_kernel<<<(N + 1 + 255) / 256, 256, 0, stream>>>(startv, cursor, bsum, N, E);
    fill_kernel<<<ebl, 256, 0, stream>>>(ei, ety, ew, cursor, csre, E);

    int abl = (N + 31) / 32;
    int gbl = (N + 127) / 128;

    // --- layer 0: xb <- relu(agg@W0 + x0@Wself0) in place; rel1 = relu(r0@Wrel0) ---
    aggregate_kernel<<<abl, 256, 0, stream>>>(xb, r0b, startv, csre, aggb, N);
    mfma_dual_gemm_kernel<<<gbl + 2, 256, 0, stream>>>(
        aggb, xb, wt0a, wt0s, nullptr, xb, N, 1,
        r0, Wr0, rel1, rel1b, R, gbl);

    // --- layer 1: out_x = agg@W1 + x1@Wself1; out_r = rel1@Wrel1 ---
    aggregate_kernel<<<abl, 256, 0, stream>>>(xb, rel1b, startv, csre, aggb, N);
    mfma_dual_gemm_kernel<<<gbl + 2, 256, 0, stream>>>(
        aggb, xb, wt1a, wt1s, out_x, nullptr, N, 0,
        rel1, Wr1, out_r, nullptr, R, gbl);
}

// Round 6
// 234.533 us; speedup vs baseline: 2.5497x; 1.3399x over previous
//
#include <hip/hip_runtime.h>

#define DD 128

typedef __attribute__((ext_vector_type(8))) short bf16x8;
typedef __attribute__((ext_vector_type(4))) float f32x4;

__device__ __forceinline__ float b2f(unsigned short u) {
    return __uint_as_float(((unsigned)u) << 16);
}
__device__ __forceinline__ unsigned short f2b(float f) {
    unsigned u = __float_as_uint(f);
    unsigned r = (u + 0x7FFFu + ((u >> 16) & 1u)) >> 16;
    return (unsigned short)r;
}

// ---------------- CSR build ----------------

__global__ __launch_bounds__(256) void scan1_kernel(const int* __restrict__ cnt,
                                                    int* __restrict__ startv,
                                                    int* __restrict__ bsum, int n) {
    int i = blockIdx.x * 256 + threadIdx.x;
    int v = (i < n) ? cnt[i] : 0;
    int lane = threadIdx.x & 63, wid = threadIdx.x >> 6;
    int incl = v;
#pragma unroll
    for (int o = 1; o < 64; o <<= 1) {
        int t = __shfl_up(incl, o);
        if (lane >= o) incl += t;
    }
    __shared__ int wsum[4];
    __shared__ int wpre[4];
    if (lane == 63) wsum[wid] = incl;
    __syncthreads();
    if (threadIdx.x == 0) {
        int s = 0;
        for (int w2 = 0; w2 < 4; ++w2) { wpre[w2] = s; s += wsum[w2]; }
        bsum[blockIdx.x] = s;
    }
    __syncthreads();
    if (i < n) startv[i] = incl - v + wpre[wid];
}

__global__ __launch_bounds__(512) void scan2_kernel(int* bsum, int nb) {
    int i = threadIdx.x;
    int v = (i < nb) ? bsum[i] : 0;
    int lane = threadIdx.x & 63, wid = threadIdx.x >> 6;
    int incl = v;
#pragma unroll
    for (int o = 1; o < 64; o <<= 1) {
        int t = __shfl_up(incl, o);
        if (lane >= o) incl += t;
    }
    __shared__ int wsum[8];
    __shared__ int wpre[8];
    if (lane == 63) wsum[wid] = incl;
    __syncthreads();
    if (threadIdx.x == 0) {
        int s = 0;
        for (int w2 = 0; w2 < 8; ++w2) { wpre[w2] = s; s += wsum[w2]; }
    }
    __syncthreads();
    if (i < nb) bsum[i] = incl - v + wpre[wid];
}

__global__ __launch_bounds__(256) void scan3_kernel(int* startv, int* cursor,
                                                    const int* __restrict__ bsum,
                                                    int n, int E) {
    int i = blockIdx.x * 256 + threadIdx.x;
    if (i < n) {
        int s = startv[i] + bsum[i >> 8];
        startv[i] = s;
        cursor[i] = s;
    } else if (i == n) {
        startv[n] = E;
    }
}

__global__ __launch_bounds__(256) void fill_kernel(const int* __restrict__ ei,
                                                   const int* __restrict__ ety,
                                                   const float* __restrict__ ew,
                                                   int* cursor,
                                                   uint2* __restrict__ csre, int E) {
    int e = blockIdx.x * 256 + threadIdx.x;
    if (e >= E) return;
    int dst = ei[E + e];
    int p = atomicAdd(&cursor[dst], 1);
    uint2 rec;
    rec.x = ((unsigned)ei[e]) | (((unsigned)ety[e]) << 20);  // src | (rel<<20)
    rec.y = __float_as_uint(ew[e]);
    csre[p] = rec;
}

// ---------------- merged conversions + histogram ----------------
// blocks: [0,bx) x0->xb ; [bx,bx+br) r0->r0b ; [.., +256) W transposes ; rest: hist

__global__ __launch_bounds__(256) void prep_hist_kernel(
    const float* __restrict__ x0, unsigned short* __restrict__ xb, int bx, int n4x,
    const float* __restrict__ r0, unsigned short* __restrict__ r0b, int br, int n4r,
    const float* __restrict__ W0, const float* __restrict__ Ws0,
    const float* __restrict__ W1, const float* __restrict__ Ws1,
    unsigned short* __restrict__ wt0a, unsigned short* __restrict__ wt0s,
    unsigned short* __restrict__ wt1a, unsigned short* __restrict__ wt1s,
    const int* __restrict__ ei, int* __restrict__ cnt, int E) {
    int bid = blockIdx.x;
    if (bid < bx) {
        int i = bid * 256 + threadIdx.x;
        if (i < n4x) {
            float4 v = ((const float4*)x0)[i];
            ((ushort4*)xb)[i] = make_ushort4(f2b(v.x), f2b(v.y), f2b(v.z), f2b(v.w));
        }
        return;
    }
    bid -= bx;
    if (bid < br) {
        int i = bid * 256 + threadIdx.x;
        if (i < n4r) {
            float4 v = ((const float4*)r0)[i];
            ((ushort4*)r0b)[i] = make_ushort4(f2b(v.x), f2b(v.y), f2b(v.z), f2b(v.w));
        }
        return;
    }
    bid -= br;
    if (bid < 256) {
        int which = bid >> 6;
        int i = (bid & 63) * 256 + threadIdx.x;  // 0..16383
        int cc = i >> 7, k = i & 127;
        const float* Wsel = which == 0 ? W0 : which == 1 ? Ws0 : which == 2 ? W1 : Ws1;
        unsigned short* Osel = which == 0 ? wt0a : which == 1 ? wt0s : which == 2 ? wt1a : wt1s;
        Osel[i] = f2b(Wsel[k * DD + cc]);      // Wt[c][k] = W[k][c]
        return;
    }
    bid -= 256;
    int e = bid * 256 + threadIdx.x;
    if (e < E) atomicAdd(&cnt[ei[E + e]], 1);
}

// ---------------- aggregation: aggb[n] = bf16( sum_e w*(x[src]-rel[t]) ) ----------------
// 16 lanes/slot, each slot owns 2 nodes (n, n+16); 2-edge unroll per node
// -> 4 independent gather chains per lane, 16 per wave.

__global__ __launch_bounds__(256) void aggregate_kernel(
    const unsigned short* __restrict__ xb, const unsigned short* __restrict__ relb,
    const int* __restrict__ startv, const uint2* __restrict__ csre,
    unsigned short* __restrict__ aggb, int n) {
    int slot = threadIdx.x >> 4;      // 0..15
    int c = threadIdx.x & 15;         // 16B chunk within the 256B bf16 row
    int n0 = blockIdx.x * 32 + slot;
    int n1 = n0 + 16;
    int i0 = 0, e0 = 0, i1 = 0, e1 = 0;
    if (n0 < n) { i0 = startv[n0]; e0 = startv[n0 + 1]; }
    if (n1 < n) { i1 = startv[n1]; e1 = startv[n1 + 1]; }
    const bf16x8* X = (const bf16x8*)xb;
    const bf16x8* Rl = (const bf16x8*)relb;
    float p0[8], q0[8], p1[8], q1[8];
#pragma unroll
    for (int j = 0; j < 8; ++j) { p0[j] = 0.f; q0[j] = 0.f; p1[j] = 0.f; q1[j] = 0.f; }
    while (i0 < e0 || i1 < e1) {
        bool v00 = i0 < e0, v01 = i0 + 1 < e0;
        bool v10 = i1 < e1, v11 = i1 + 1 < e1;
        uint2 c00 = csre[v00 ? i0 : 0];
        uint2 c01 = csre[v01 ? i0 + 1 : 0];
        uint2 c10 = csre[v10 ? i1 : 0];
        uint2 c11 = csre[v11 ? i1 + 1 : 0];
        float w00 = v00 ? __uint_as_float(c00.y) : 0.f;
        float w01 = v01 ? __uint_as_float(c01.y) : 0.f;
        float w10 = v10 ? __uint_as_float(c10.y) : 0.f;
        float w11 = v11 ? __uint_as_float(c11.y) : 0.f;
        bf16x8 x00 = X[(size_t)(c00.x & 0xFFFFFu) * 16 + c];
        bf16x8 x01 = X[(size_t)(c01.x & 0xFFFFFu) * 16 + c];
        bf16x8 x10 = X[(size_t)(c10.x & 0xFFFFFu) * 16 + c];
        bf16x8 x11 = X[(size_t)(c11.x & 0xFFFFFu) * 16 + c];
        bf16x8 r00 = Rl[(c00.x >> 20) * 16 + c];
        bf16x8 r01 = Rl[(c01.x >> 20) * 16 + c];
        bf16x8 r10 = Rl[(c10.x >> 20) * 16 + c];
        bf16x8 r11 = Rl[(c11.x >> 20) * 16 + c];
#pragma unroll
        for (int j = 0; j < 8; ++j) {
            p0[j] += (b2f((unsigned short)x00[j]) - b2f((unsigned short)r00[j])) * w00;
            q0[j] += (b2f((unsigned short)x01[j]) - b2f((unsigned short)r01[j])) * w01;
            p1[j] += (b2f((unsigned short)x10[j]) - b2f((unsigned short)r10[j])) * w10;
            q1[j] += (b2f((unsigned short)x11[j]) - b2f((unsigned short)r11[j])) * w11;
        }
        i0 = min(i0 + 2, e0);
        i1 = min(i1 + 2, e1);
    }
    if (n0 < n) {
        bf16x8 ov;
#pragma unroll
        for (int j = 0; j < 8; ++j) ov[j] = (short)f2b(p0[j] + q0[j]);
        ((bf16x8*)aggb)[(size_t)n0 * 16 + c] = ov;
    }
    if (n1 < n) {
        bf16x8 ov;
#pragma unroll
        for (int j = 0; j < 8; ++j) ov[j] = (short)f2b(p1[j] + q1[j]);
        ((bf16x8*)aggb)[(size_t)n1 * 16 + c] = ov;
    }
}

// ---------------- fused dual GEMM via MFMA (swapped operands, 512 threads) ----------
// out = A@W + X@Wself. 8 waves/block, 16 rows/wave -> 16 waves/CU at 64KB LDS.
// mfma(Wfrag, Afrag) yields C^T layout: lane (lr,lk) holds
// C[row=base+lr][ct*16 + lk*4 + reg] -> one f32x4/bf16x4 store per tile.

__global__ __launch_bounds__(512, 4) void mfma_dual_gemm_kernel(
    const unsigned short* __restrict__ A, const unsigned short* __restrict__ X,
    const unsigned short* __restrict__ WtA, const unsigned short* __restrict__ WtX,
    float* __restrict__ outf, unsigned short* __restrict__ outb,
    int nrows, int relu) {
    __shared__ unsigned short sW[2][DD * DD];   // 64 KB
    for (int i = threadIdx.x; i < 2048; i += 512) {
        int row = i >> 4, slot = i & 15;
        int so = (slot ^ (row & 15)) * 8;
        *(float4*)&sW[0][row * DD + so] = ((const float4*)WtA)[i];
        *(float4*)&sW[1][row * DD + so] = ((const float4*)WtX)[i];
    }
    __syncthreads();
    int w = threadIdx.x >> 6, l = threadIdx.x & 63;
    int lr = l & 15, lk = l >> 4;
    int row = blockIdx.x * 128 + w * 16 + lr;
    bool v = row < nrows;

    f32x4 acc[8];
#pragma unroll
    for (int ct = 0; ct < 8; ++ct) acc[ct] = (f32x4){0.f, 0.f, 0.f, 0.f};

#pragma unroll
    for (int kb = 0; kb < 4; ++kb) {
        int koff = kb * 32 + lk * 8;
        bf16x8 a = {}, x = {};
        if (v) {
            a = *(const bf16x8*)(A + (size_t)row * DD + koff);
            x = *(const bf16x8*)(X + (size_t)row * DD + koff);
        }
#pragma unroll
        for (int ct = 0; ct < 8; ++ct) {
            int wrow = ct * 16 + lr;
            int slot = kb * 4 + lk;
            int so = (slot ^ (wrow & 15)) * 8;
            bf16x8 bw = *(const bf16x8*)&sW[0][wrow * DD + so];
            bf16x8 bs = *(const bf16x8*)&sW[1][wrow * DD + so];
            acc[ct] = __builtin_amdgcn_mfma_f32_16x16x32_bf16(bw, a, acc[ct], 0, 0, 0);
            acc[ct] = __builtin_amdgcn_mfma_f32_16x16x32_bf16(bs, x, acc[ct], 0, 0, 0);
        }
    }

    if (v) {
#pragma unroll
        for (int ct = 0; ct < 8; ++ct) {
            f32x4 vv = acc[ct];
            if (relu) {
                vv[0] = fmaxf(vv[0], 0.f); vv[1] = fmaxf(vv[1], 0.f);
                vv[2] = fmaxf(vv[2], 0.f); vv[3] = fmaxf(vv[3], 0.f);
            }
            int cb = ct * 16 + lk * 4;
            if (outf) *(f32x4*)(outf + (size_t)row * DD + cb) = vv;
            if (outb) {
                *(ushort4*)(outb + (size_t)row * DD + cb) =
                    make_ushort4(f2b(vv[0]), f2b(vv[1]), f2b(vv[2]), f2b(vv[3]));
            }
        }
    }
}

// ---------------- small f32 GEMM (rel path, 200 rows), optional bf16 copy ----------------

__global__ __launch_bounds__(256) void gemm128_kernel(const float* A,
                                                      const float* __restrict__ W,
                                                      float* out, unsigned short* outb,
                                                      int nrows, int relu) {
    __shared__ float sW[DD * DD];
    {
        float4* d = (float4*)sW;
        const float4* s = (const float4*)W;
        for (int i = threadIdx.x; i < DD * DD / 4; i += 256) d[i] = s[i];
    }
    __syncthreads();
    int j4 = (threadIdx.x & 31) << 2;
    int rslot = threadIdx.x >> 5;
    int base = blockIdx.x * 32;
    for (int r0 = 0; r0 < 32; r0 += 8) {
        int row = base + r0 + rslot;
        if (row < nrows) {
            const float4* A4 = (const float4*)(A + (size_t)row * DD);
            float4 acc = make_float4(0.f, 0.f, 0.f, 0.f);
#pragma unroll
            for (int k4 = 0; k4 < 32; ++k4) {
                float4 av = A4[k4];
                const float* wp = sW + (k4 * 4) * DD + j4;
                float4 w0 = *(const float4*)(wp);
                float4 w1 = *(const float4*)(wp + DD);
                float4 w2 = *(const float4*)(wp + 2 * DD);
                float4 w3 = *(const float4*)(wp + 3 * DD);
                acc.x += av.x * w0.x + av.y * w1.x + av.z * w2.x + av.w * w3.x;
                acc.y += av.x * w0.y + av.y * w1.y + av.z * w2.y + av.w * w3.y;
                acc.z += av.x * w0.z + av.y * w1.z + av.z * w2.z + av.w * w3.z;
                acc.w += av.x * w0.w + av.y * w1.w + av.z * w2.w + av.w * w3.w;
            }
            if (relu) {
                acc.x = fmaxf(acc.x, 0.f); acc.y = fmaxf(acc.y, 0.f);
                acc.z = fmaxf(acc.z, 0.f); acc.w = fmaxf(acc.w, 0.f);
            }
            if (out) *(float4*)(out + (size_t)row * DD + j4) = acc;
            if (outb) {
                ushort4 o = make_ushort4(f2b(acc.x), f2b(acc.y), f2b(acc.z), f2b(acc.w));
                *(ushort4*)(outb + (size_t)row * DD + j4) = o;
            }
        }
    }
}

// ---------------- launcher ----------------

extern "C" void kernel_launch(void* const* d_in, const int* in_sizes, int n_in,
                              void* d_out, int out_size, void* d_ws, size_t ws_size,
                              hipStream_t stream) {
    const int*   ei  = (const int*)d_in[0];
    const int*   ety = (const int*)d_in[1];
    const float* ew  = (const float*)d_in[2];
    const float* x0  = (const float*)d_in[3];
    const float* r0  = (const float*)d_in[4];
    const float* W0  = (const float*)d_in[5];
    const float* Ws0 = (const float*)d_in[6];
    const float* Wr0 = (const float*)d_in[7];
    const float* W1  = (const float*)d_in[8];
    const float* Ws1 = (const float*)d_in[9];
    const float* Wr1 = (const float*)d_in[10];

    const int E = in_sizes[1];
    const int N = in_sizes[3] / DD;
    const int R = in_sizes[4] / DD;

    float* out_x = (float*)d_out;                 // [N,128] f32
    float* out_r = out_x + (size_t)N * DD;        // [R,128] f32

    char* w = (char*)d_ws;
    size_t off = 0;
    auto alloc = [&](size_t bytes) {
        void* p = w + off;
        off += (bytes + 255) & ~(size_t)255;
        return p;
    };
    unsigned short* aggb  = (unsigned short*)alloc((size_t)N * DD * 2);  // 25.6 MB
    unsigned short* xb    = (unsigned short*)alloc((size_t)N * DD * 2);  // 25.6 MB
    unsigned short* r0b   = (unsigned short*)alloc((size_t)R * DD * 2);
    unsigned short* rel1b = (unsigned short*)alloc((size_t)R * DD * 2);
    unsigned short* wt0a  = (unsigned short*)alloc((size_t)DD * DD * 2);
    unsigned short* wt0s  = (unsigned short*)alloc((size_t)DD * DD * 2);
    unsigned short* wt1a  = (unsigned short*)alloc((size_t)DD * DD * 2);
    unsigned short* wt1s  = (unsigned short*)alloc((size_t)DD * DD * 2);
    float* rel1   = (float*)alloc((size_t)R * DD * 4);
    int*   startv = (int*)alloc((size_t)(N + 1) * 4);
    int*   cursor = (int*)alloc((size_t)N * 4);
    int*   bsum   = (int*)alloc(512 * 4);
    uint2* csre   = (uint2*)alloc((size_t)E * 8);
    (void)ws_size; (void)n_in; (void)out_size;

    // --- CSR build + conversions ---
    int* cnt = cursor;
    hipMemsetAsync(cnt, 0, (size_t)N * 4, stream);
    int ebl = (E + 255) / 256;
    int nb  = (N + 255) / 256;
    int n4x = N * 32, n4r = R * 32;
    int bx = (n4x + 255) / 256, br = (n4r + 255) / 256;
    prep_hist_kernel<<<bx + br + 256 + ebl, 256, 0, stream>>>(
        x0, xb, bx, n4x, r0, r0b, br, n4r,
        W0, Ws0, W1, Ws1, wt0a, wt0s, wt1a, wt1s, ei, cnt, E);
    scan1_kernel<<<nb, 256, 0, stream>>>(cnt, startv, bsum, N);
    scan2_kernel<<<1, 512, 0, stream>>>(bsum, nb);
    scan3_kernel<<<(N + 1 + 255) / 256, 256, 0, stream>>>(startv, cursor, bsum, N, E);
    fill_kernel<<<ebl, 256, 0, stream>>>(ei, ety, ew, cursor, csre, E);

    int abl = (N + 31) / 32;
    int gbl = (N + 127) / 128;
    int rbl = (R + 31) / 32;

    // --- layer 0: xb <- relu(agg@W0 + x0@Wself0) in place; rel1 = relu(r0@Wrel0) ---
    aggregate_kernel<<<abl, 256, 0, stream>>>(xb, r0b, startv, csre, aggb, N);
    mfma_dual_gemm_kernel<<<gbl, 512, 0, stream>>>(aggb, xb, wt0a, wt0s,
                                                   nullptr, xb, N, 1);
    gemm128_kernel<<<rbl, 256, 0, stream>>>(r0, Wr0, rel1, rel1b, R, 1);

    // --- layer 1: out_x = agg@W1 + x1@Wself1; out_r = rel1@Wrel1 ---
    aggregate_kernel<<<abl, 256, 0, stream>>>(xb, rel1b, startv, csre, aggb, N);
    mfma_dual_gemm_kernel<<<gbl, 512, 0, stream>>>(aggb, xb, wt1a, wt1s,
                                                   out_x, nullptr, N, 0);
    gemm128_kernel<<<rbl, 256, 0, stream>>>(rel1, Wr1, out_r, nullptr, R, 0);
}